// Round 1
// baseline (99.005 us; speedup 1.0000x reference)
//
#include <hip/hip_runtime.h>
#include <math.h>

// Problem constants (fixed by setup_inputs)
constexpr int BB = 512;    // batch
constexpr int DD = 512;    // features
constexpr int CC = 1000;   // classes
constexpr float EPSF = 0.3f;

// ws layout (bytes):
//   [0,    2048)  : j[512]       int32   predicted class per row
//   [2048, 4096)  : ymax[512]    float
//   [4096, 8192)  : norm[1024]   float   column squared-norms (1000 used)
//   [8192, 16384) : partial[512*4] float per-(b, c-tile) block maxima
// total 16 KB — well within any ws_size.

__global__ __launch_bounds__(256) void lm_prep(const float* __restrict__ y,
                                               const float* __restrict__ kW,
                                               int* __restrict__ wj,
                                               float* __restrict__ wymax,
                                               float* __restrict__ wnorm) {
  __shared__ float sv[4];
  __shared__ int si[4];
  __shared__ float ns[256];

  const int t = threadIdx.x;
  const int blk = blockIdx.x;

  if (blk < BB) {
    // ---- per-row argmax + max value (lowest-index tie-break, matches jnp.argmax) ----
    const float* yr = y + (size_t)blk * CC;
    float bv = -INFINITY;
    int bi = 0;
    for (int c = t; c < CC; c += 256) {
      float v = yr[c];
      if (v > bv || (v == bv && c < bi)) { bv = v; bi = c; }
    }
    for (int off = 32; off > 0; off >>= 1) {
      float ov = __shfl_down(bv, off);
      int oi = __shfl_down(bi, off);
      if (ov > bv || (ov == bv && oi < bi)) { bv = ov; bi = oi; }
    }
    if ((t & 63) == 0) { sv[t >> 6] = bv; si[t >> 6] = bi; }
    __syncthreads();
    if (t == 0) {
      for (int w = 1; w < 4; ++w) {
        if (sv[w] > bv || (sv[w] == bv && si[w] < bi)) { bv = sv[w]; bi = si[w]; }
      }
      wj[blk] = bi;
      wymax[blk] = bv;
    }
  } else {
    // ---- column squared-norms: 8 blocks, each covers 128 columns, 2 d-halves ----
    const int nb = blk - BB;          // 0..7
    const int clocal = t & 127;
    const int part = t >> 7;          // 0 or 1
    const int c = nb * 128 + clocal;
    float s = 0.f;
    if (c < CC) {
      const float* wp = kW + (size_t)part * 256 * CC + c;
      #pragma unroll 8
      for (int d = 0; d < 256; ++d) {
        float w = wp[(size_t)d * CC];
        s += w * w;
      }
    }
    ns[t] = s;
    __syncthreads();
    if (t < 128 && c < CC) wnorm[c] = ns[t] + ns[t + 128];
  }
}

__global__ __launch_bounds__(256) void lm_main(const float* __restrict__ y,
                                               const float* __restrict__ kW,
                                               const int* __restrict__ wj,
                                               const float* __restrict__ wymax,
                                               const float* __restrict__ wnorm,
                                               float* __restrict__ out,
                                               float* __restrict__ partial) {
  __shared__ __align__(16) float qt[DD * 8];  // [d][bb] gathered predicted-class columns
  __shared__ int sj[8];
  __shared__ float snq[8];
  __shared__ float symax[8];
  __shared__ float red[8][4];

  const int t = threadIdx.x;
  const int ct = blockIdx.x;             // c-tile 0..3
  const int b0 = blockIdx.y * 8;         // batch tile base
  const int c = ct * 256 + t;
  const bool valid = (c < CC);
  const int cl = valid ? c : 0;

  if (t < 8) {
    int j = wj[b0 + t];
    sj[t] = j;
    snq[t] = wnorm[j];
    symax[t] = wymax[b0 + t];
  }
  __syncthreads();

  // stage the 8 predicted-class columns into LDS (scattered, L2-hot, once/block)
  for (int idx = t; idx < DD * 8; idx += 256) {
    int d = idx >> 3, bb = idx & 7;
    qt[idx] = kW[(size_t)d * CC + sj[bb]];
  }
  __syncthreads();

  // d-loop: dot(col_j[bb], col_c) for 8 b's simultaneously
  float acc[8];
  #pragma unroll
  for (int i = 0; i < 8; ++i) acc[i] = 0.f;

  const float* wp = kW + cl;
  #pragma unroll 8
  for (int d = 0; d < DD; ++d) {
    float w = wp[(size_t)d * CC];
    float4 qa = *(const float4*)(qt + d * 8);
    float4 qb = *(const float4*)(qt + d * 8 + 4);
    acc[0] += qa.x * w; acc[1] += qa.y * w; acc[2] += qa.z * w; acc[3] += qa.w * w;
    acc[4] += qb.x * w; acc[5] += qb.y * w; acc[6] += qb.z * w; acc[7] += qb.w * w;
  }

  const float nc = wnorm[cl];

  #pragma unroll
  for (int bb = 0; bb < 8; ++bb) {
    const int b = b0 + bb;
    float yv = y[(size_t)b * CC + cl];
    float k2 = snq[bb] + nc - 2.f * acc[bb];
    float Kd = sqrtf(fmaxf(k2, 0.f) + 1e-10f);
    float cd = (!valid || yv == symax[bb]) ? -INFINITY : yv + EPSF * Kd;
    if (valid) out[(size_t)b * (CC + 1) + c] = yv;  // fused y-copy
    for (int off = 32; off > 0; off >>= 1) cd = fmaxf(cd, __shfl_down(cd, off));
    if ((t & 63) == 0) red[bb][t >> 6] = cd;
  }
  __syncthreads();
  if (t < 8) {
    float m = fmaxf(fmaxf(red[t][0], red[t][1]), fmaxf(red[t][2], red[t][3]));
    partial[(size_t)(b0 + t) * 4 + ct] = m;
  }
}

__global__ __launch_bounds__(256) void lm_final(const float* __restrict__ partial,
                                                float* __restrict__ out) {
  const int b = blockIdx.x * 256 + threadIdx.x;
  if (b < BB) {
    const float* p = partial + (size_t)b * 4;
    out[(size_t)b * (CC + 1) + CC] = fmaxf(fmaxf(p[0], p[1]), fmaxf(p[2], p[3]));
  }
}

extern "C" void kernel_launch(void* const* d_in, const int* in_sizes, int n_in,
                              void* d_out, int out_size, void* d_ws, size_t ws_size,
                              hipStream_t stream) {
  const float* y = (const float*)d_in[0];    // [512, 1000]
  const float* kW = (const float*)d_in[1];   // [512, 1000]
  float* out = (float*)d_out;                // [512, 1001]

  char* ws = (char*)d_ws;
  int* wj = (int*)(ws + 0);
  float* wymax = (float*)(ws + 2048);
  float* wnorm = (float*)(ws + 4096);
  float* partial = (float*)(ws + 8192);

  lm_prep<<<BB + 8, 256, 0, stream>>>(y, kW, wj, wymax, wnorm);
  lm_main<<<dim3(4, 64), 256, 0, stream>>>(y, kW, wj, wymax, wnorm, out, partial);
  lm_final<<<2, 256, 0, stream>>>(partial, out);
}

// Round 2
// 94.897 us; speedup vs baseline: 1.0433x; 1.0433x over previous
//
#include <hip/hip_runtime.h>
#include <math.h>

// Problem constants (fixed by setup_inputs)
constexpr int BB = 512;    // batch
constexpr int DD = 512;    // features
constexpr int CC = 1000;   // classes
constexpr float EPSF = 0.3f;

// ws layout (bytes):
//   [0, 8192) : partial[512*4] float — per-(b, c-tile) block maxima
//
// Fused design: ONE main kernel (grid 4 c-tiles × 64 b-tiles) computes, per
// block: per-row argmax of its 8 y-rows (32-lane group per row, y is L3-hot),
// stages the 8 predicted-class kW columns in LDS, then a d-loop computing
// dot(col_j[bb], col_c) for all 8 b's per thread while ALSO accumulating
// norm(col_c) inline (w*w). norm(col_j) comes from the staged LDS columns.
// K^2 = n_j + n_c - 2*dot. Epilogue fuses the y-copy into out and reduces the
// masked candidate max per (b, c-tile) into ws; a tiny second kernel reduces
// the 4 c-tile partials.

__global__ __launch_bounds__(256) void lm_main(const float* __restrict__ y,
                                               const float* __restrict__ kW,
                                               float* __restrict__ out,
                                               float* __restrict__ partial) {
  __shared__ __align__(16) float qt[DD * 8];  // [d][bb] gathered predicted-class columns
  __shared__ int sj[8];
  __shared__ float snq[8];
  __shared__ float symax[8];
  __shared__ float red[8][4];

  const int t = threadIdx.x;
  const int ct = blockIdx.x;             // c-tile 0..3
  const int b0 = blockIdx.y * 8;         // batch tile base
  const int c = ct * 256 + t;
  const bool valid = (c < CC);
  const int cl = valid ? c : 0;

  const int g = t >> 5;                  // 32-lane group 0..7 (one per batch row)
  const int rel = t & 31;

  // ---- per-row argmax + max (lowest-index tie-break, matches jnp.argmax) ----
  {
    const float* yr = y + (size_t)(b0 + g) * CC;
    float bv = -INFINITY;
    int bi = 0;
    for (int cc = rel; cc < CC; cc += 32) {
      float v = yr[cc];
      if (v > bv) { bv = v; bi = cc; }   // strided scan is increasing -> '>' keeps lowest idx
    }
    #pragma unroll
    for (int off = 16; off > 0; off >>= 1) {
      float ov = __shfl_down(bv, off);
      int oi = __shfl_down(bi, off);
      if (ov > bv || (ov == bv && oi < bi)) { bv = ov; bi = oi; }
    }
    if (rel == 0) { sj[g] = bi; symax[g] = bv; }
  }
  __syncthreads();

  // ---- stage the 8 predicted-class columns into LDS (scattered, L2-hot) ----
  for (int idx = t; idx < DD * 8; idx += 256) {
    int d = idx >> 3, bb = idx & 7;
    qt[idx] = kW[(size_t)d * CC + sj[bb]];
  }
  __syncthreads();

  // ---- norms of the gathered columns, from LDS ----
  {
    float s = 0.f;
    for (int d = rel; d < DD; d += 32) s += qt[d * 8 + g] * qt[d * 8 + g];
    #pragma unroll
    for (int off = 16; off > 0; off >>= 1) s += __shfl_down(s, off);
    if (rel == 0) snq[g] = s;
  }
  __syncthreads();

  // ---- d-loop: dot(col_j[bb], col_c) for 8 b's + inline norm(col_c) ----
  float acc[8];
  #pragma unroll
  for (int i = 0; i < 8; ++i) acc[i] = 0.f;
  float nc = 0.f;

  const float* wp = kW + cl;
  #pragma unroll 8
  for (int d = 0; d < DD; ++d) {
    float w = wp[(size_t)d * CC];
    float4 qa = *(const float4*)(qt + d * 8);
    float4 qb = *(const float4*)(qt + d * 8 + 4);
    nc += w * w;
    acc[0] += qa.x * w; acc[1] += qa.y * w; acc[2] += qa.z * w; acc[3] += qa.w * w;
    acc[4] += qb.x * w; acc[5] += qb.y * w; acc[6] += qb.z * w; acc[7] += qb.w * w;
  }

  // ---- epilogue: candidate, mask, fused y-copy, per-(b, c-tile) max ----
  #pragma unroll
  for (int bb = 0; bb < 8; ++bb) {
    const int b = b0 + bb;
    float yv = y[(size_t)b * CC + cl];
    float k2 = snq[bb] + nc - 2.f * acc[bb];
    float Kd = sqrtf(fmaxf(k2, 0.f) + 1e-10f);
    float cd = (!valid || yv == symax[bb]) ? -INFINITY : yv + EPSF * Kd;
    if (valid) out[(size_t)b * (CC + 1) + c] = yv;  // fused y-copy
    #pragma unroll
    for (int off = 32; off > 0; off >>= 1) cd = fmaxf(cd, __shfl_down(cd, off));
    if ((t & 63) == 0) red[bb][t >> 6] = cd;
  }
  __syncthreads();
  if (t < 8) {
    float m = fmaxf(fmaxf(red[t][0], red[t][1]), fmaxf(red[t][2], red[t][3]));
    partial[(size_t)(b0 + t) * 4 + ct] = m;
  }
}

__global__ __launch_bounds__(256) void lm_final(const float* __restrict__ partial,
                                                float* __restrict__ out) {
  const int b = blockIdx.x * 256 + threadIdx.x;
  if (b < BB) {
    const float* p = partial + (size_t)b * 4;
    out[(size_t)b * (CC + 1) + CC] = fmaxf(fmaxf(p[0], p[1]), fmaxf(p[2], p[3]));
  }
}

extern "C" void kernel_launch(void* const* d_in, const int* in_sizes, int n_in,
                              void* d_out, int out_size, void* d_ws, size_t ws_size,
                              hipStream_t stream) {
  const float* y = (const float*)d_in[0];    // [512, 1000]
  const float* kW = (const float*)d_in[1];   // [512, 1000]
  float* out = (float*)d_out;                // [512, 1001]

  float* partial = (float*)d_ws;             // [512, 4]

  lm_main<<<dim3(4, 64), 256, 0, stream>>>(y, kW, out, partial);
  lm_final<<<2, 256, 0, stream>>>(partial, out);
}

// Round 3
// 88.041 us; speedup vs baseline: 1.1245x; 1.0779x over previous
//
#include <hip/hip_runtime.h>
#include <math.h>

// Problem constants (fixed by setup_inputs)
constexpr int BB = 512;    // batch
constexpr int DD = 512;    // features
constexpr int CC = 1000;   // classes
constexpr int CP = 1024;   // padded class count for partial rows (16B-aligned float4)
constexpr float EPSF = 0.3f;
constexpr int NCH = 8;           // d-chunks (parallelism over the reduction dim)
constexpr int DCH = DD / NCH;    // 64 d per chunk
constexpr int BT = 8;            // batch rows per block

// ws layout (bytes):
//   [0, 16 MB)        : partial[NCH][BB][CP]  float — per-chunk partial dots
//   [16 MB, +32 KB)   : normp[NCH][CP]        float — per-chunk partial column norms
//
// Identity: K[b,c]^2 = ||col_j||^2 + ||col_c||^2 - 2*dot(col_j, col_c), summed
// over 8 d-chunks. lm_dots computes per-chunk dots (+ norms); lm_combine sums
// chunks, computes argmax/ymax itself (mask is value-based), K, candidates,
// fused y-copy, and the full row max in one block per row.

__global__ __launch_bounds__(256) void lm_dots(const float* __restrict__ y,
                                               const float* __restrict__ kW,
                                               float* __restrict__ partial,
                                               float* __restrict__ normp) {
  __shared__ __align__(16) float qt[DCH * BT];  // [dd][bb] gathered j-columns, this chunk
  __shared__ int sj[BT];

  const int t = threadIdx.x;
  const int chunk = blockIdx.x;        // 0..7
  const int b0 = blockIdx.y * BT;      // batch tile base
  const int d0 = chunk * DCH;
  const int g = t >> 5, rel = t & 31;  // 32-lane group per batch row

  // ---- per-row argmax index (lowest-index tie-break, matches jnp.argmax) ----
  {
    const float* yr = y + (size_t)(b0 + g) * CC;
    float bv = -INFINITY;
    int bi = 0;
    for (int cc = rel; cc < CC; cc += 32) {
      float v = yr[cc];
      if (v > bv) { bv = v; bi = cc; }   // ascending scan -> '>' keeps lowest idx
    }
    #pragma unroll
    for (int off = 16; off > 0; off >>= 1) {
      float ov = __shfl_down(bv, off);
      int   oi = __shfl_down(bi, off);
      if (ov > bv || (ov == bv && oi < bi)) { bv = ov; bi = oi; }
    }
    if (rel == 0) sj[g] = bi;
  }
  __syncthreads();

  // ---- stage this chunk's slice of the 8 predicted-class columns ----
  for (int idx = t; idx < DCH * BT; idx += 256) {
    int dd = idx >> 3, bb = idx & 7;
    qt[idx] = kW[(size_t)(d0 + dd) * CC + sj[bb]];
  }
  __syncthreads();

  const int c4 = t * 4;                // 4 consecutive classes per thread
  if (c4 >= CC) return;                // no barriers after this point

  float4 acc[BT];
  #pragma unroll
  for (int i = 0; i < BT; ++i) acc[i] = make_float4(0.f, 0.f, 0.f, 0.f);
  float4 n4 = make_float4(0.f, 0.f, 0.f, 0.f);

  const float* wp = kW + (size_t)d0 * CC + c4;
  #pragma unroll 4
  for (int dd = 0; dd < DCH; ++dd) {
    const float4 w  = *(const float4*)(wp + (size_t)dd * CC);
    const float4 qa = *(const float4*)(qt + dd * 8);
    const float4 qb = *(const float4*)(qt + dd * 8 + 4);
    n4.x += w.x * w.x; n4.y += w.y * w.y; n4.z += w.z * w.z; n4.w += w.w * w.w;
    acc[0].x += qa.x * w.x; acc[0].y += qa.x * w.y; acc[0].z += qa.x * w.z; acc[0].w += qa.x * w.w;
    acc[1].x += qa.y * w.x; acc[1].y += qa.y * w.y; acc[1].z += qa.y * w.z; acc[1].w += qa.y * w.w;
    acc[2].x += qa.z * w.x; acc[2].y += qa.z * w.y; acc[2].z += qa.z * w.z; acc[2].w += qa.z * w.w;
    acc[3].x += qa.w * w.x; acc[3].y += qa.w * w.y; acc[3].z += qa.w * w.z; acc[3].w += qa.w * w.w;
    acc[4].x += qb.x * w.x; acc[4].y += qb.x * w.y; acc[4].z += qb.x * w.z; acc[4].w += qb.x * w.w;
    acc[5].x += qb.y * w.x; acc[5].y += qb.y * w.y; acc[5].z += qb.y * w.z; acc[5].w += qb.y * w.w;
    acc[6].x += qb.z * w.x; acc[6].y += qb.z * w.y; acc[6].z += qb.z * w.z; acc[6].w += qb.z * w.w;
    acc[7].x += qb.w * w.x; acc[7].y += qb.w * w.y; acc[7].z += qb.w * w.z; acc[7].w += qb.w * w.w;
  }

  #pragma unroll
  for (int bb = 0; bb < BT; ++bb) {
    *(float4*)(partial + ((size_t)chunk * BB + (b0 + bb)) * CP + c4) = acc[bb];
  }
  if (blockIdx.y == 0) {
    *(float4*)(normp + (size_t)chunk * CP + c4) = n4;
  }
}

__global__ __launch_bounds__(256) void lm_combine(const float* __restrict__ y,
                                                  const float* __restrict__ partial,
                                                  const float* __restrict__ normp,
                                                  float* __restrict__ out) {
  __shared__ float swv[4];
  __shared__ int   swi[4];
  __shared__ float sred[4];
  __shared__ float s_ymax;
  __shared__ float s_nj;

  const int b = blockIdx.x;
  const int t = threadIdx.x;
  const int c4 = t * 4;
  const bool act = (c4 < CC);          // 250*4 == 1000, exact coverage
  const int w = t >> 6, lane = t & 63;

  float4 yv = make_float4(-INFINITY, -INFINITY, -INFINITY, -INFINITY);
  if (act) yv = *(const float4*)(y + (size_t)b * CC + c4);

  // ---- block argmax: value (for the eq-mask) + index (for norm[j] lookup) ----
  float bv = yv.x; int bi = c4;
  if (yv.y > bv) { bv = yv.y; bi = c4 + 1; }
  if (yv.z > bv) { bv = yv.z; bi = c4 + 2; }
  if (yv.w > bv) { bv = yv.w; bi = c4 + 3; }
  #pragma unroll
  for (int off = 32; off > 0; off >>= 1) {
    float ov = __shfl_down(bv, off);
    int   oi = __shfl_down(bi, off);
    if (ov > bv || (ov == bv && oi < bi)) { bv = ov; bi = oi; }
  }
  if (lane == 0) { swv[w] = bv; swi[w] = bi; }
  __syncthreads();
  if (t == 0) {
    for (int i = 1; i < 4; ++i)
      if (swv[i] > bv || (swv[i] == bv && swi[i] < bi)) { bv = swv[i]; bi = swi[i]; }
    s_ymax = bv;
    float nj = 0.f;
    #pragma unroll
    for (int ch = 0; ch < NCH; ++ch) nj += normp[(size_t)ch * CP + bi];
    s_nj = nj;
  }
  __syncthreads();
  const float ymax = s_ymax;
  const float nj = s_nj;

  float4 cd = make_float4(-INFINITY, -INFINITY, -INFINITY, -INFINITY);
  if (act) {
    float4 dot = make_float4(0.f, 0.f, 0.f, 0.f);
    float4 nc  = make_float4(0.f, 0.f, 0.f, 0.f);
    #pragma unroll
    for (int ch = 0; ch < NCH; ++ch) {
      const float4 p  = *(const float4*)(partial + ((size_t)ch * BB + b) * CP + c4);
      const float4 np = *(const float4*)(normp + (size_t)ch * CP + c4);
      dot.x += p.x; dot.y += p.y; dot.z += p.z; dot.w += p.w;
      nc.x += np.x; nc.y += np.y; nc.z += np.z; nc.w += np.w;
    }
    const float k2x = nj + nc.x - 2.f * dot.x;
    const float k2y = nj + nc.y - 2.f * dot.y;
    const float k2z = nj + nc.z - 2.f * dot.z;
    const float k2w = nj + nc.w - 2.f * dot.w;
    cd.x = (yv.x == ymax) ? -INFINITY : yv.x + EPSF * sqrtf(fmaxf(k2x, 0.f) + 1e-10f);
    cd.y = (yv.y == ymax) ? -INFINITY : yv.y + EPSF * sqrtf(fmaxf(k2y, 0.f) + 1e-10f);
    cd.z = (yv.z == ymax) ? -INFINITY : yv.z + EPSF * sqrtf(fmaxf(k2z, 0.f) + 1e-10f);
    cd.w = (yv.w == ymax) ? -INFINITY : yv.w + EPSF * sqrtf(fmaxf(k2w, 0.f) + 1e-10f);

    float* orow = out + (size_t)b * (CC + 1) + c4;   // fused y-copy (4B-aligned stores)
    orow[0] = yv.x; orow[1] = yv.y; orow[2] = yv.z; orow[3] = yv.w;
  }

  float m = fmaxf(fmaxf(cd.x, cd.y), fmaxf(cd.z, cd.w));
  #pragma unroll
  for (int off = 32; off > 0; off >>= 1) m = fmaxf(m, __shfl_down(m, off));
  if (lane == 0) sred[w] = m;
  __syncthreads();
  if (t == 0) {
    out[(size_t)b * (CC + 1) + CC] =
        fmaxf(fmaxf(sred[0], sred[1]), fmaxf(sred[2], sred[3]));
  }
}

extern "C" void kernel_launch(void* const* d_in, const int* in_sizes, int n_in,
                              void* d_out, int out_size, void* d_ws, size_t ws_size,
                              hipStream_t stream) {
  const float* y = (const float*)d_in[0];    // [512, 1000]
  const float* kW = (const float*)d_in[1];   // [512, 1000]
  float* out = (float*)d_out;                // [512, 1001]

  char* ws = (char*)d_ws;
  float* partial = (float*)ws;                                   // 8*512*1024*4 = 16 MB
  float* normp = (float*)(ws + (size_t)NCH * BB * CP * 4);       // 8*1024*4 = 32 KB

  lm_dots<<<dim3(NCH, BB / BT), 256, 0, stream>>>(y, kW, partial, normp);
  lm_combine<<<BB, 256, 0, stream>>>(y, partial, normp, out);
}

// Round 4
// 83.867 us; speedup vs baseline: 1.1805x; 1.0498x over previous
//
#include <hip/hip_runtime.h>
#include <math.h>

// Problem constants (fixed by setup_inputs)
constexpr int BB = 512;    // batch
constexpr int DD = 512;    // features
constexpr int CC = 1000;   // classes
constexpr int CP = 1024;   // padded class count (16B-aligned float4 rows)
constexpr float EPSF = 0.3f;
constexpr int NCH = 16;          // d-chunks (TLP over the reduction dim): 1024 blocks = 4/CU
constexpr int DCH = DD / NCH;    // 32 d per chunk
constexpr int BT  = 8;           // batch rows per block
constexpr int PF  = 8;           // prefetch depth (rotating register buffer)

// ws layout (bytes):
//   [0, 32 MB)            : partial[NCH][BB][CP] float — per-chunk dots
//   [32 MB, +64 KB)       : normp[NCH][CP]       float — per-chunk column norms
//   [+64 KB, +2 KB)       : wj[BB]    int   — argmax class per row
//   [+2 KB,  +2 KB)       : wymax[BB] float — row max
//
// K[b,c]^2 = ||col_j||^2 + ||col_c||^2 - 2*dot(col_j, col_c), chunk-summed.

__global__ __launch_bounds__(256) void lm_argmax(const float* __restrict__ y,
                                                 int* __restrict__ wj,
                                                 float* __restrict__ wymax) {
  const int t = threadIdx.x;
  const int wv = t >> 6, lane = t & 63;
  const int b = blockIdx.x * 4 + wv;          // one wave per row
  const float* yr = y + (size_t)b * CC;

  float bv = -INFINITY; int bi = 0;
  #pragma unroll
  for (int k = 0; k < 4; ++k) {
    const int c4 = (lane + k * 64) * 4;       // ascending per thread -> '>' keeps lowest idx
    if (c4 < CC) {
      const float4 v = *(const float4*)(yr + c4);
      if (v.x > bv) { bv = v.x; bi = c4; }
      if (v.y > bv) { bv = v.y; bi = c4 + 1; }
      if (v.z > bv) { bv = v.z; bi = c4 + 2; }
      if (v.w > bv) { bv = v.w; bi = c4 + 3; }
    }
  }
  #pragma unroll
  for (int off = 32; off > 0; off >>= 1) {
    const float ov = __shfl_down(bv, off);
    const int   oi = __shfl_down(bi, off);
    if (ov > bv || (ov == bv && oi < bi)) { bv = ov; bi = oi; }
  }
  if (lane == 0) { wj[b] = bi; wymax[b] = bv; }
}

__global__ __launch_bounds__(256) void lm_dots(const float* __restrict__ kW,
                                               const int* __restrict__ wj,
                                               float* __restrict__ partial,
                                               float* __restrict__ normp) {
  __shared__ __align__(16) float qt[DCH * BT];   // [dd][bb], 1 KB
  __shared__ int sj[BT];

  const int t = threadIdx.x;
  const int chunk = blockIdx.x;        // 0..15
  const int b0 = blockIdx.y * BT;
  const int d0 = chunk * DCH;

  if (t < BT) sj[t] = wj[b0 + t];
  __syncthreads();
  // stage this chunk's slice of the 8 j-columns: exactly one load per thread
  qt[t] = kW[(size_t)(d0 + (t >> 3)) * CC + sj[t & 7]];
  __syncthreads();

  const int c4 = t * 4;
  if (c4 >= CC) return;                // no barriers below

  float4 acc[BT];
  #pragma unroll
  for (int i = 0; i < BT; ++i) acc[i] = make_float4(0.f, 0.f, 0.f, 0.f);
  float4 n4 = make_float4(0.f, 0.f, 0.f, 0.f);

  const float* wp = kW + (size_t)d0 * CC + c4;

  // software pipeline: rotating PF-deep prefetch, fully unrolled (static idx)
  float4 wbuf[PF];
  #pragma unroll
  for (int p = 0; p < PF; ++p) wbuf[p] = *(const float4*)(wp + (size_t)p * CC);

  #pragma unroll
  for (int dd = 0; dd < DCH; ++dd) {
    const float4 w = wbuf[dd & (PF - 1)];
    if (dd + PF < DCH)
      wbuf[dd & (PF - 1)] = *(const float4*)(wp + (size_t)(dd + PF) * CC);
    const float4 qa = *(const float4*)(qt + dd * 8);
    const float4 qb = *(const float4*)(qt + dd * 8 + 4);
    n4.x += w.x * w.x; n4.y += w.y * w.y; n4.z += w.z * w.z; n4.w += w.w * w.w;
    acc[0].x += qa.x * w.x; acc[0].y += qa.x * w.y; acc[0].z += qa.x * w.z; acc[0].w += qa.x * w.w;
    acc[1].x += qa.y * w.x; acc[1].y += qa.y * w.y; acc[1].z += qa.y * w.z; acc[1].w += qa.y * w.w;
    acc[2].x += qa.z * w.x; acc[2].y += qa.z * w.y; acc[2].z += qa.z * w.z; acc[2].w += qa.z * w.w;
    acc[3].x += qa.w * w.x; acc[3].y += qa.w * w.y; acc[3].z += qa.w * w.z; acc[3].w += qa.w * w.w;
    acc[4].x += qb.x * w.x; acc[4].y += qb.x * w.y; acc[4].z += qb.x * w.z; acc[4].w += qb.x * w.w;
    acc[5].x += qb.y * w.x; acc[5].y += qb.y * w.y; acc[5].z += qb.y * w.z; acc[5].w += qb.y * w.w;
    acc[6].x += qb.z * w.x; acc[6].y += qb.z * w.y; acc[6].z += qb.z * w.z; acc[6].w += qb.z * w.w;
    acc[7].x += qb.w * w.x; acc[7].y += qb.w * w.y; acc[7].z += qb.w * w.z; acc[7].w += qb.w * w.w;
  }

  #pragma unroll
  for (int bb = 0; bb < BT; ++bb)
    *(float4*)(partial + ((size_t)chunk * BB + (b0 + bb)) * CP + c4) = acc[bb];
  if (blockIdx.y == 0)
    *(float4*)(normp + (size_t)chunk * CP + c4) = n4;
}

__global__ __launch_bounds__(256) void lm_combine(const float* __restrict__ y,
                                                  const float* __restrict__ partial,
                                                  const float* __restrict__ normp,
                                                  const int* __restrict__ wj,
                                                  const float* __restrict__ wymax,
                                                  float* __restrict__ out) {
  __shared__ float sred[4];
  __shared__ int s_bi;
  __shared__ float s_ymax;
  __shared__ float s_nj;

  const int b = blockIdx.x;
  const int t = threadIdx.x;
  const int c4 = t * 4;
  const bool act = (c4 < CC);
  const int w = t >> 6, lane = t & 63;

  if (t == 0) { s_bi = wj[b]; s_ymax = wymax[b]; }
  __syncthreads();

  // norm of the predicted-class column: 16 parallel lane loads + shuffle reduce
  if (t < NCH) {
    float v = normp[(size_t)t * CP + s_bi];
    #pragma unroll
    for (int off = 8; off > 0; off >>= 1) v += __shfl_down(v, off);
    if (t == 0) s_nj = v;
  }

  float4 dot = make_float4(0.f, 0.f, 0.f, 0.f);
  float4 nc  = make_float4(0.f, 0.f, 0.f, 0.f);
  float4 yv  = make_float4(-INFINITY, -INFINITY, -INFINITY, -INFINITY);
  if (act) {
    yv = *(const float4*)(y + (size_t)b * CC + c4);
    #pragma unroll
    for (int ch = 0; ch < NCH; ++ch) {
      const float4 p  = *(const float4*)(partial + ((size_t)ch * BB + b) * CP + c4);
      const float4 np = *(const float4*)(normp + (size_t)ch * CP + c4);
      dot.x += p.x; dot.y += p.y; dot.z += p.z; dot.w += p.w;
      nc.x += np.x; nc.y += np.y; nc.z += np.z; nc.w += np.w;
    }
  }
  __syncthreads();
  const float ymax = s_ymax;
  const float nj = s_nj;

  float4 cd = make_float4(-INFINITY, -INFINITY, -INFINITY, -INFINITY);
  if (act) {
    const float k2x = nj + nc.x - 2.f * dot.x;
    const float k2y = nj + nc.y - 2.f * dot.y;
    const float k2z = nj + nc.z - 2.f * dot.z;
    const float k2w = nj + nc.w - 2.f * dot.w;
    cd.x = (yv.x == ymax) ? -INFINITY : yv.x + EPSF * sqrtf(fmaxf(k2x, 0.f) + 1e-10f);
    cd.y = (yv.y == ymax) ? -INFINITY : yv.y + EPSF * sqrtf(fmaxf(k2y, 0.f) + 1e-10f);
    cd.z = (yv.z == ymax) ? -INFINITY : yv.z + EPSF * sqrtf(fmaxf(k2z, 0.f) + 1e-10f);
    cd.w = (yv.w == ymax) ? -INFINITY : yv.w + EPSF * sqrtf(fmaxf(k2w, 0.f) + 1e-10f);

    float* orow = out + (size_t)b * (CC + 1) + c4;   // fused y-copy
    orow[0] = yv.x; orow[1] = yv.y; orow[2] = yv.z; orow[3] = yv.w;
  }

  float m = fmaxf(fmaxf(cd.x, cd.y), fmaxf(cd.z, cd.w));
  #pragma unroll
  for (int off = 32; off > 0; off >>= 1) m = fmaxf(m, __shfl_down(m, off));
  if (lane == 0) sred[w] = m;
  __syncthreads();
  if (t == 0)
    out[(size_t)b * (CC + 1) + CC] =
        fmaxf(fmaxf(sred[0], sred[1]), fmaxf(sred[2], sred[3]));
}

extern "C" void kernel_launch(void* const* d_in, const int* in_sizes, int n_in,
                              void* d_out, int out_size, void* d_ws, size_t ws_size,
                              hipStream_t stream) {
  const float* y  = (const float*)d_in[0];   // [512, 1000]
  const float* kW = (const float*)d_in[1];   // [512, 1000]
  float* out = (float*)d_out;                // [512, 1001]

  char* ws = (char*)d_ws;
  float* partial = (float*)ws;                                     // 32 MB
  float* normp   = (float*)(ws + (size_t)NCH * BB * CP * 4);       // 64 KB
  int*   wjp     = (int*)(ws + (size_t)NCH * BB * CP * 4 + (size_t)NCH * CP * 4);
  float* wymaxp  = (float*)((char*)wjp + BB * 4);

  lm_argmax<<<BB / 4, 256, 0, stream>>>(y, wjp, wymaxp);
  lm_dots<<<dim3(NCH, BB / BT), 256, 0, stream>>>(kW, wjp, partial, normp);
  lm_combine<<<BB, 256, 0, stream>>>(y, partial, normp, wjp, wymaxp, out);
}